// Round 2
// baseline (821.093 us; speedup 1.0000x reference)
//
#include <hip/hip_runtime.h>
#include <hip/hip_bf16.h>

#define E_TOTAL   1600000
#define NV        50000
#define DE        64
#define DV        64
#define DIN       192
#define DHID      128
#define DOUT      64
#define TILE_M    64
#define XS        200          // xb row stride (ushorts), 400 B: dword-stride 100 ≡ 4 mod 32 -> min-aliasing b128 reads
#define HS        136          // hb row stride (ushorts), 272 B: dword-stride 68 ≡ 4 mod 32 -> min-aliasing b128 reads
#define NTILES    (E_TOTAL / TILE_M)   // 25000 exact

typedef __bf16 bf16x8  __attribute__((ext_vector_type(8)));
typedef __bf16 bf16x4  __attribute__((ext_vector_type(4)));
typedef float  floatx4 __attribute__((ext_vector_type(4)));
typedef float  fx4     __attribute__((ext_vector_type(4)));

static __device__ __forceinline__ unsigned short f2bf(float f) {
    unsigned int u = __float_as_uint(f);
    u += 0x7fffu + ((u >> 16) & 1u);   // round-to-nearest-even
    return (unsigned short)(u >> 16);
}

// ---- prep: W1 [192][128] -> w1t bf16 [128][192]; W2 [128][64] -> w2t bf16 [64][128];
//      vfeat fp32 [NV][64] -> vfb bf16 (same layout)
__global__ void prep_kernel(const float* __restrict__ W1, const float* __restrict__ W2,
                            const float* __restrict__ vfeat,
                            unsigned short* __restrict__ w1t,
                            unsigned short* __restrict__ w2t,
                            unsigned short* __restrict__ vfb, int do_vfb) {
    int tid = blockIdx.x * blockDim.x + threadIdx.x;
    int stride = gridDim.x * blockDim.x;
    for (int i = tid; i < DIN * DHID; i += stride) {
        int n = i / DIN, k = i % DIN;
        w1t[i] = f2bf(W1[k * DHID + n]);
    }
    for (int i = tid; i < DHID * DOUT; i += stride) {
        int n = i / DHID, k = i % DHID;
        w2t[i] = f2bf(W2[k * DOUT + n]);
    }
    if (do_vfb) {
        const fx4* src = (const fx4*)vfeat;
        ushort4* dst = (ushort4*)vfb;
        int n4 = NV * DV / 4;
        for (int i = tid; i < n4; i += stride) {
            fx4 v = src[i];
            ushort4 o;
            o.x = f2bf(v[0]); o.y = f2bf(v[1]); o.z = f2bf(v[2]); o.w = f2bf(v[3]);
            dst[i] = o;
        }
    }
}

// Round-2 structure: back to the serial round-0 schedule (compiler-scheduled,
// TLP across ~12 waves/CU hides gather latency — m114 implicit overlap), but
// keeping round-1's operand-swap epilogues:
//   L1 computes mfma(W1^T-frag, x-frag) -> lane holds 4 consecutive k of h
//     -> relu+pack -> single ds_write_b64 per fragment (8 LDS writes vs 32)
//   L2 computes mfma(W2^T-frag, h-frag) -> lane holds 4 consecutive out floats
//     -> 16-B vectorized REGULAR store (no nontemporal: the nt hint evicted
//        half-dirty 128-B lines before the sibling wave's 64-B half arrived,
//        1.69x write amplification measured in round 1)
// No sched_barrier / setprio (m141/m190: both hurt lockstep structures).
// Exactly 2 barriers/tile: stage(t+1) touches only xb (all xb reads done
// before the L1->L2 barrier); hb(t) reads finish before any wave passes the
// post-stage barrier into L1(t+1).
template <bool USE_VFB>
__global__ __launch_bounds__(256, 2) void edge_mlp(
    const float* __restrict__ edata,
    const float* __restrict__ vfeat,
    const float* __restrict__ b1,
    const float* __restrict__ b2,
    const int* __restrict__ senders,
    const int* __restrict__ receivers,
    const unsigned short* __restrict__ w1t,
    const unsigned short* __restrict__ w2t,
    const unsigned short* __restrict__ vfb,
    float* __restrict__ out) {
    __shared__ unsigned short xb[TILE_M * XS];   // 25600 B
    __shared__ unsigned short hb[TILE_M * HS];   // 17408 B

    const int tid  = threadIdx.x;
    const int lane = tid & 63;
    const int wave = tid >> 6;
    const int l15  = lane & 15;
    const int quad = lane >> 4;

    // ---- per-wave weight fragments in registers (MFMA A-operand layout:
    // lane&15 = row(n), k = quad*8+j)
    bf16x8 w1f[6][2];   // rows n = wave*32 + nb*16 + l15 of W1^T [128][192]
    bf16x8 w2f[4];      // rows n = wave*16 + l15 of W2^T [64][128]
    {
        for (int nb = 0; nb < 2; ++nb) {
            int n = wave * 32 + nb * 16 + l15;
            const unsigned short* p = w1t + n * DIN + quad * 8;
            for (int ks = 0; ks < 6; ++ks)
                w1f[ks][nb] = *(const bf16x8*)(p + ks * 32);
        }
        int n2 = wave * 16 + l15;
        const unsigned short* p2 = w2t + n2 * DHID + quad * 8;
        for (int ks = 0; ks < 4; ++ks)
            w2f[ks] = *(const bf16x8*)(p2 + ks * 32);
    }
    // With swapped operands, C row = quad*4 + r indexes the *n* dimension.
    float b1v[2][4], b2v[4];
#pragma unroll
    for (int nb = 0; nb < 2; ++nb)
#pragma unroll
        for (int r = 0; r < 4; ++r)
            b1v[nb][r] = b1[wave * 32 + nb * 16 + quad * 4 + r];
#pragma unroll
    for (int r = 0; r < 4; ++r)
        b2v[r] = b2[wave * 16 + quad * 4 + r];

    for (int t = blockIdx.x; t < NTILES; t += gridDim.x) {
        const long e0 = (long)t * TILE_M;

        // ---- stage x tile: [64 edges][192 bf16] = edata | vfeat[recv] | vfeat[send]
        {
            // edata: 64 edges x 16 float4 (streaming: keep nt on LOADS)
#pragma unroll
            for (int it = 0; it < 4; ++it) {
                int idx = it * 256 + tid;
                int e = idx >> 4;
                int c = idx & 15;
                fx4 v = __builtin_nontemporal_load((const fx4*)(edata + (e0 + e) * DE + c * 4));
                bf16x4 o;
                o[0] = (__bf16)v[0]; o[1] = (__bf16)v[1];
                o[2] = (__bf16)v[2]; o[3] = (__bf16)v[3];
                *(bf16x4*)(xb + e * XS + c * 4) = o;
            }
            if constexpr (USE_VFB) {
                // bf16 vertex table: 64 edges x 2 gathers x 8 chunks of 16B
#pragma unroll
                for (int it = 0; it < 4; ++it) {
                    int idx = it * 256 + tid;
                    int e = idx >> 4;
                    int g = (idx >> 3) & 1;
                    int c = idx & 7;
                    int row = g ? senders[e0 + e] : receivers[e0 + e];
                    uint4 v = *(const uint4*)(vfb + row * DV + c * 8);
                    *(uint4*)(xb + e * XS + DE + g * DV + c * 8) = v;
                }
            } else {
                // fp32 vertex table fallback
#pragma unroll
                for (int it = 0; it < 8; ++it) {
                    int idx = it * 256 + tid;
                    int e = idx >> 5;
                    int g = (idx >> 4) & 1;
                    int c = idx & 15;
                    int row = g ? senders[e0 + e] : receivers[e0 + e];
                    fx4 v = *(const fx4*)(vfeat + (long)row * DV + c * 4);
                    bf16x4 o;
                    o[0] = (__bf16)v[0]; o[1] = (__bf16)v[1];
                    o[2] = (__bf16)v[2]; o[3] = (__bf16)v[3];
                    *(bf16x4*)(xb + e * XS + DE + g * DV + c * 4) = o;
                }
            }
        }
        __syncthreads();

        // ---- layer 1: C = mfma(W1^T-frag, x-frag) -> lane holds h[e][k0..k0+3]
        floatx4 acc[4][2];
#pragma unroll
        for (int mb = 0; mb < 4; ++mb)
#pragma unroll
            for (int nb = 0; nb < 2; ++nb)
                acc[mb][nb] = (floatx4){b1v[nb][0], b1v[nb][1], b1v[nb][2], b1v[nb][3]};
#pragma unroll
        for (int ks = 0; ks < 6; ++ks) {
            bf16x8 a[4];
#pragma unroll
            for (int mb = 0; mb < 4; ++mb)
                a[mb] = *(const bf16x8*)(xb + (mb * 16 + l15) * XS + ks * 32 + quad * 8);
#pragma unroll
            for (int mb = 0; mb < 4; ++mb)
#pragma unroll
                for (int nb = 0; nb < 2; ++nb)
                    acc[mb][nb] = __builtin_amdgcn_mfma_f32_16x16x32_bf16(
                        w1f[ks][nb], a[mb], acc[mb][nb], 0, 0, 0);
        }

        // relu + pack: lane (quad,l15) holds h[mb*16+l15][wave*32+nb*16+quad*4 + r]
        // -> 4 consecutive k => single 8-B LDS write, k-contiguous hb[64][HS]
#pragma unroll
        for (int mb = 0; mb < 4; ++mb)
#pragma unroll
            for (int nb = 0; nb < 2; ++nb) {
                bf16x4 o;
#pragma unroll
                for (int r = 0; r < 4; ++r) {
                    float v = acc[mb][nb][r];
                    o[r] = (__bf16)(v > 0.f ? v : 0.f);
                }
                *(bf16x4*)(hb + (mb * 16 + l15) * HS + wave * 32 + nb * 16 + quad * 4) = o;
            }
        __syncthreads();   // hb ready; all xb(t) reads done

        // ---- layer 2: C = mfma(W2^T-frag, h-frag) -> lane holds out[e][n0..n0+3]
        floatx4 acc2[4];
#pragma unroll
        for (int mb = 0; mb < 4; ++mb)
            acc2[mb] = (floatx4){b2v[0], b2v[1], b2v[2], b2v[3]};
#pragma unroll
        for (int ks = 0; ks < 4; ++ks)
#pragma unroll
            for (int mb = 0; mb < 4; ++mb) {
                bf16x8 a2 = *(const bf16x8*)(hb + (mb * 16 + l15) * HS + ks * 32 + quad * 8);
                acc2[mb] = __builtin_amdgcn_mfma_f32_16x16x32_bf16(w2f[ks], a2, acc2[mb], 0, 0, 0);
            }

        // store: 16-B vectorized, REGULAR store so L2 merges the four 64-B
        // wave-fragments of each 256-B row into full-line evictions
#pragma unroll
        for (int mb = 0; mb < 4; ++mb)
            *(fx4*)(out + (e0 + mb * 16 + l15) * DOUT + wave * 16 + quad * 4) = acc2[mb];
        // no third barrier: next tile's stage only writes xb, and every wave's
        // xb reads completed before the hb barrier above
    }
}

extern "C" void kernel_launch(void* const* d_in, const int* in_sizes, int n_in,
                              void* d_out, int out_size, void* d_ws, size_t ws_size,
                              hipStream_t stream) {
    const float* edata     = (const float*)d_in[0];
    const float* vfeat     = (const float*)d_in[1];
    const float* W1        = (const float*)d_in[2];
    const float* b1        = (const float*)d_in[3];
    const float* W2        = (const float*)d_in[4];
    const float* b2        = (const float*)d_in[5];
    const int*   senders   = (const int*)d_in[6];
    const int*   receivers = (const int*)d_in[7];
    float* out = (float*)d_out;

    unsigned short* w1t = (unsigned short*)d_ws;
    unsigned short* w2t = w1t + DIN * DHID;
    unsigned short* vfb = w2t + DHID * DOUT;
    const size_t need_vfb = (size_t)(DIN * DHID + DHID * DOUT + NV * DV) * sizeof(unsigned short);
    const bool use_vfb = ws_size >= need_vfb;

    prep_kernel<<<512, 256, 0, stream>>>(W1, W2, vfeat, w1t, w2t, vfb, use_vfb ? 1 : 0);
    if (use_vfb)
        edge_mlp<true><<<1536, 256, 0, stream>>>(edata, vfeat, b1, b2, senders, receivers,
                                                 w1t, w2t, vfb, out);
    else
        edge_mlp<false><<<1536, 256, 0, stream>>>(edata, vfeat, b1, b2, senders, receivers,
                                                  w1t, w2t, vfb, out);
}